// Round 2
// baseline (958.846 us; speedup 1.0000x reference)
//
#include <hip/hip_runtime.h>

#define BATCH 2
#define NN 8192
#define DD 256

typedef __attribute__((ext_vector_type(8))) short bf16x8;   // 8 bf16 = 4 VGPR
typedef __attribute__((ext_vector_type(4))) float f32x4;

__device__ __forceinline__ unsigned short f2bf(float f) {
    unsigned u = __builtin_bit_cast(unsigned, f);
    u += 0x7fffu + ((u >> 16) & 1u);          // RNE
    return (unsigned short)(u >> 16);
}

__device__ __forceinline__ bf16x8 cvt8(f32x4 lo, f32x4 hi) {
    bf16x8 r;
#pragma unroll
    for (int i = 0; i < 4; ++i) {
        r[i]     = (short)f2bf(lo[i]);
        r[i + 4] = (short)f2bf(hi[i]);
    }
    return r;
}

// ---- kernel 1: fused logmap0-scale + transpose to bf16 ----
// xtf[b][kb][d][nn] : nn = k within 64-row tile -> B fragments are 16B-contiguous
__global__ void k_prep(const float* __restrict__ x, unsigned short* __restrict__ xtf) {
    __shared__ __align__(16) unsigned short T[DD][72];   // [d][r], stride 72 breaks conflicts
    int bid = blockIdx.x;                  // 0..255
    int b = bid >> 7, kb = bid & 127;
    int bn0 = b * NN + kb * 64;
    int t = threadIdx.x;
    int r = t >> 2, cc = t & 3;            // row-in-tile, 64-col chunk
    const float4* rp = (const float4*)(x + (size_t)(bn0 + r) * DD + cc * 64);
    float4 v[16];
    float s = 0.0f;
#pragma unroll
    for (int j4 = 0; j4 < 16; ++j4) {
        v[j4] = rp[j4];
        s += v[j4].x * v[j4].x + v[j4].y * v[j4].y + v[j4].z * v[j4].z + v[j4].w * v[j4].w;
    }
    s += __shfl_xor(s, 1, 64);
    s += __shfl_xor(s, 2, 64);             // full-row sumsq across the 4 quarter-lanes
    float n = fmaxf(sqrtf(s), 1e-15f);
    float z = fminf(n, 1.0f - 1e-7f);
    float sc = (0.5f * logf((1.0f + z) / (1.0f - z))) / n;   // artanh(n)/n
#pragma unroll
    for (int j4 = 0; j4 < 16; ++j4) {
        int d = cc * 64 + j4 * 4;
        T[d + 0][r] = f2bf(v[j4].x * sc);
        T[d + 1][r] = f2bf(v[j4].y * sc);
        T[d + 2][r] = f2bf(v[j4].z * sc);
        T[d + 3][r] = f2bf(v[j4].w * sc);
    }
    __syncthreads();
    unsigned short* outp = xtf + (size_t)(b * 128 + kb) * DD * 64;
    int dd = t >> 3, ccc = t & 7;
#pragma unroll
    for (int p = 0; p < 8; ++p) {
        int d = dd + 32 * p;
        bf16x8 val = *(const bf16x8*)&T[d][ccc * 8];
        *(bf16x8*)(outp + (size_t)d * 64 + ccc * 8) = val;   // coalesced 4KB/instr
    }
}

// ---- kernel 2: barrier-free GEMM + fused expmap0/project epilogue ----
// 256 blocks (1/CU), 4 waves; wave quadrant: 32 rows x 128 cols.
// A loaded straight from global in fragment layout (fp32->bf16 in regs), NO LDS,
// NO __syncthreads in the K-loop -> vmcnt pipelining never drains.
struct ABuf { f32x4 a[2][2][2]; };   // [mt][kk][half]
struct BBuf { bf16x8 f[8][2]; };     // [nt][kk]

__device__ __forceinline__ void load_tiles(const float* abase, const unsigned short* bbase,
                                           int kb, ABuf& A, BBuf& B) {
#pragma unroll
    for (int mt = 0; mt < 2; ++mt)
#pragma unroll
        for (int kk = 0; kk < 2; ++kk) {
            const f32x4* p = (const f32x4*)(abase + (size_t)mt * 16 * NN + (size_t)kb * 64 + kk * 32);
            A.a[mt][kk][0] = __builtin_nontemporal_load(p);       // nt: keep xt hot in L2
            A.a[mt][kk][1] = __builtin_nontemporal_load(p + 1);
        }
    const unsigned short* bk = bbase + (size_t)kb * DD * 64;
#pragma unroll
    for (int nt = 0; nt < 8; ++nt)
#pragma unroll
        for (int kk = 0; kk < 2; ++kk)
            B.f[nt][kk] = *(const bf16x8*)(bk + nt * 16 * 64 + kk * 32);
}

__device__ __forceinline__ void compute_tiles(const ABuf& A, const BBuf& B, f32x4 acc[2][8]) {
#pragma unroll
    for (int kk = 0; kk < 2; ++kk) {
        bf16x8 af[2];
#pragma unroll
        for (int mt = 0; mt < 2; ++mt) af[mt] = cvt8(A.a[mt][kk][0], A.a[mt][kk][1]);
#pragma unroll
        for (int mt = 0; mt < 2; ++mt)
#pragma unroll
            for (int nt = 0; nt < 8; ++nt)
                acc[mt][nt] = __builtin_amdgcn_mfma_f32_16x16x32_bf16(
                    af[mt], B.f[nt][kk], acc[mt][nt], 0, 0, 0);
    }
}

__global__ __launch_bounds__(256, 1) void k_gemm(const float* __restrict__ adj,
                                                 const unsigned short* __restrict__ xtf,
                                                 float* __restrict__ out) {
    __shared__ float red[2][64];
    __shared__ float rowscale[64];

    int bid = blockIdx.x;
    // XCD swizzle: XCDs 0-3 -> batch 0, 4-7 -> batch 1 (each XCD L2 holds one batch's 4MiB xt)
    int xcd = bid & 7;
    int b = xcd >> 2;
    int mtile = ((bid >> 3) << 2) | (xcd & 3);   // bijective over 0..127
    int m0 = mtile * 64;

    int t = threadIdx.x;
    int w = t >> 6, lane = t & 63, c = lane & 15, q = lane >> 4;
    int wm = w >> 1, wn = w & 1;

    // A fragment address: row = m0 + wm*32 + mt*16 + c ; k = kb*64 + kk*32 + q*8
    const float* abase = adj + (size_t)b * NN * NN + (size_t)(m0 + wm * 32 + c) * NN + q * 8;
    // B fragment address: d = wn*128 + nt*16 + c ; k-in-tile = kk*32 + q*8
    const unsigned short* bbase = xtf + (size_t)b * 128 * DD * 64
                                + (size_t)(wn * 128 + c) * 64 + q * 8;

    f32x4 acc[2][8];
#pragma unroll
    for (int mt = 0; mt < 2; ++mt)
#pragma unroll
        for (int nt = 0; nt < 8; ++nt)
#pragma unroll
            for (int rg = 0; rg < 4; ++rg) acc[mt][nt][rg] = 0.0f;

    ABuf A0, A1;
    BBuf B0, B1;
    load_tiles(abase, bbase, 0, A0, B0);
    for (int kb = 0; kb < 128; kb += 2) {
        load_tiles(abase, bbase, kb + 1, A1, B1);
        compute_tiles(A0, B0, acc);
        if (kb + 2 < 128) load_tiles(abase, bbase, kb + 2, A0, B0);
        compute_tiles(A1, B1, acc);
    }

    // ---- epilogue: row norm over full D=256 (two wn-waves), scale, store ----
    // C/D layout: col = c, row-in-16 = q*4 + rg
#pragma unroll
    for (int mt = 0; mt < 2; ++mt)
#pragma unroll
        for (int rg = 0; rg < 4; ++rg) {
            float v = 0.0f;
#pragma unroll
            for (int nt = 0; nt < 8; ++nt) v += acc[mt][nt][rg] * acc[mt][nt][rg];
            v += __shfl_xor(v, 1, 64);
            v += __shfl_xor(v, 2, 64);
            v += __shfl_xor(v, 4, 64);
            v += __shfl_xor(v, 8, 64);     // sum over the 16 c-lanes
            if (c == 0) red[wn][wm * 32 + mt * 16 + q * 4 + rg] = v;
        }
    __syncthreads();
    if (t < 64) {
        float tot = red[0][t] + red[1][t];
        float n = fmaxf(sqrtf(tot), 1e-15f);
        rowscale[t] = fminf(tanhf(n), 1.0f - 4e-3f) / n;   // expmap0 + project fused
    }
    __syncthreads();

    float* obase = out + ((size_t)(b * NN + m0 + wm * 32)) * DD + wn * 128 + c;
#pragma unroll
    for (int mt = 0; mt < 2; ++mt)
#pragma unroll
        for (int rg = 0; rg < 4; ++rg) {
            int row = mt * 16 + q * 4 + rg;
            float rs = rowscale[wm * 32 + row];
            float* orow = obase + (size_t)row * DD;
#pragma unroll
            for (int nt = 0; nt < 8; ++nt)
                __builtin_nontemporal_store(acc[mt][nt][rg] * rs, orow + nt * 16);
        }
}

extern "C" void kernel_launch(void* const* d_in, const int* in_sizes, int n_in,
                              void* d_out, int out_size, void* d_ws, size_t ws_size,
                              hipStream_t stream) {
    const float* x   = (const float*)d_in[0];   // [2, 8192, 256] fp32
    const float* adj = (const float*)d_in[1];   // [2, 8192, 8192] fp32
    float* out = (float*)d_out;                 // [2, 8192, 256] fp32

    unsigned short* xtf = (unsigned short*)d_ws;   // 8 MiB bf16 xt^T tiles

    k_prep<<<BATCH * 128, 256, 0, stream>>>(x, xtf);
    k_gemm<<<256, 256, 0, stream>>>(adj, xtf, out);
}